// Round 2
// baseline (87.723 us; speedup 1.0000x reference)
//
#include <hip/hip_runtime.h>

// GeometryAwareCostVolume — MI355X (gfx950)
//
// Algebraic restructuring vs reference (unchanged):
//  * geo pyramid == feat pyramid: compute once, write twice.
//  * integer dx taps -> shared lerp fraction per level; 10 consecutive pooled
//    bins per level suffice.
//  * cost volume is linear in fmap2 -> pool fmap2 rows hierarchically first,
//    one dot8 per pooled bin; 131 MB cost volume never materialized.
//
// Round 2: the kernel is a memory mover (59 MB write-once out, 13 MB read-once
// in) running at ~35-40% HBM efficiency; LDS/VALU restructure in round 1 was
// exactly neutral -> critical path is the global write stream. This round:
// non-temporal (streaming) stores for the output and non-temporal loads for
// the read-once fmap inputs, so the 59 MB write stream doesn't churn the L2
// as allocate-dirty-evict traffic. Everything else is identical to round 1.

namespace {
constexpr int B_ = 2, C_ = 64, H_ = 80, W_ = 160;
constexpr int G_ = 8, GC_ = 8, L_ = 4, K_ = 9, R_ = 4;
constexpr int HW_ = H_ * W_;
constexpr int NCH_ = 2 * L_ * G_ * K_;  // 576 output channels
constexpr int TPB = 192;                 // 3 waves; 160 active in compute phase
constexpr int P_ = 5;                    // zero-pad granules each side
constexpr float INV_SQRT_GC = 0.35355339059327373f;  // 1/sqrt(8)

// padded widths (granules of 4 floats) per level
constexpr int N0 = W_ + 2 * P_;       // 170
constexpr int N1 = W_ / 2 + 2 * P_;   // 90
constexpr int N2 = W_ / 4 + 2 * P_;   // 50
constexpr int N3 = W_ / 8 + 2 * P_;   // 30
// float offsets of the 8 arrays inside one shared buffer (A=c0..3, B=c4..7)
constexpr int OFF_A0 = 0;
constexpr int OFF_B0 = OFF_A0 + N0 * 4;
constexpr int OFF_A1 = OFF_B0 + N0 * 4;
constexpr int OFF_B1 = OFF_A1 + N1 * 4;
constexpr int OFF_A2 = OFF_B1 + N1 * 4;
constexpr int OFF_B2 = OFF_A2 + N2 * 4;
constexpr int OFF_A3 = OFF_B2 + N2 * 4;
constexpr int OFF_B3 = OFF_A3 + N3 * 4;
constexpr int STOT = OFF_B3 + N3 * 4;   // 2720 floats = 10.88 KB
__device__ constexpr int AOFF[8] = {OFF_A0, OFF_B0, OFF_A1, OFF_B1,
                                    OFF_A2, OFF_B2, OFF_A3, OFF_B3};
}

// pair-mean pool one level (both halves); WD = dst interior width
template <int SA, int SB, int DA, int DB, int WD>
__device__ __forceinline__ void pool_pair(float* S, int tid) {
  for (int idx = tid; idx < 2 * WD; idx += TPB) {
    const int srcOff = (idx & 1) ? SB : SA;
    const int dstOff = (idx & 1) ? DB : DA;
    const int t = idx >> 1;
    const float4 x = *(const float4*)(S + srcOff + (P_ + 2 * t) * 4);
    const float4 y = *(const float4*)(S + srcOff + (P_ + 2 * t) * 4 + 4);
    float4 r;
    r.x = 0.5f * (x.x + y.x);
    r.y = 0.5f * (x.y + y.y);
    r.z = 0.5f * (x.z + y.z);
    r.w = 0.5f * (x.w + y.w);
    *(float4*)(S + dstOff + (P_ + t) * 4) = r;
  }
}

__global__ __launch_bounds__(TPB) void gacv_kernel(
    const float* __restrict__ fmap1, const float* __restrict__ fmap2,
    const float* __restrict__ coords, float* __restrict__ out) {
  __shared__ __align__(16) float S[STOT];

  const int tid = threadIdx.x;
  const int bid = blockIdx.x;  // (b*G_ + g)*H_ + h
  const int h = bid % H_;
  const int bg = bid / H_;
  const int g = bg % G_;
  const int b = bg / G_;

  // ---- phase 1: zero guard bins (80 granules) + stage f2 row interior
  if (tid < 80) {
    const int arr = tid / 10;          // which of the 8 arrays
    const int j = tid % 10;            // which pad granule
    const int Wl = W_ >> (arr >> 1);
    const int gr = (j < P_) ? j : (Wl + j);  // [0,5) and [Wl+5, Wl+10)
    float4 z;
    z.x = z.y = z.z = z.w = 0.0f;
    *(float4*)(S + AOFF[arr] + gr * 4) = z;
  }
  const float* f2base = fmap2 + (size_t)(b * C_ + g * GC_) * HW_ + h * W_;
  for (int idx = tid; idx < W_ * GC_; idx += TPB) {
    const int v = idx % W_;            // lanes walk v => coalesced global reads
    const int c = idx / W_;
    // read-once data: stream it (nt), don't displace L2
    const float x = __builtin_nontemporal_load(f2base + c * HW_ + v);
    // c 0..3 -> A0 half, c 4..7 -> B0 half (B0 contiguous after A0)
    S[OFF_A0 + (c >> 2) * (N0 * 4) + (v + P_) * 4 + (c & 3)] = x;
  }
  __syncthreads();
  // ---- hierarchical pair-mean pyramid (matches reference association)
  pool_pair<OFF_A0, OFF_B0, OFF_A1, OFF_B1, 80>(S, tid);
  __syncthreads();
  pool_pair<OFF_A1, OFF_B1, OFF_A2, OFF_B2, 40>(S, tid);
  __syncthreads();
  pool_pair<OFF_A2, OFF_B2, OFF_A3, OFF_B3, 20>(S, tid);
  __syncthreads();

  if (tid >= W_) return;
  const int w = tid;

  // per-thread f1 fragment, pre-scaled by 1/sqrt(gc)
  const float* f1base = fmap1 + (size_t)(b * C_ + g * GC_) * HW_ + h * W_ + w;
  float f1v[GC_];
#pragma unroll
  for (int c = 0; c < GC_; ++c)
    f1v[c] = __builtin_nontemporal_load(f1base + c * HW_) * INV_SQRT_GC;

  const float cx = coords[(b * H_ + h) * W_ + w];
  float* outb = out + (size_t)b * NCH_ * HW_ + h * W_ + w;
  const int gk = g * K_;

#pragma unroll
  for (int i = 0; i < L_; ++i) {
    const int Wl = W_ >> i;
    const float xl = cx * (1.0f / (1 << i));
    const float F = floorf(xl);
    int fi = (int)F;
    const float w1 = xl - F;  // shared lerp fraction (dx taps are integers)
    const float w0 = 1.0f - w1;
    fi = min(max(fi, 0), Wl - 1);  // safety clamp; no-op for valid coords

    // all 20 reads are base+imm off these two addresses; guard bins give the
    // exact zero the reference mask requires for out-of-range taps
    const float* Abase = S + AOFF[2 * i] + (fi + P_ - R_) * 4;
    const float* Bbase = S + AOFF[2 * i + 1] + (fi + P_ - R_) * 4;

    float4 av[2 * R_ + 2], bv[2 * R_ + 2];
#pragma unroll
    for (int j = 0; j < 2 * R_ + 2; ++j) av[j] = *(const float4*)(Abase + j * 4);
#pragma unroll
    for (int j = 0; j < 2 * R_ + 2; ++j) bv[j] = *(const float4*)(Bbase + j * 4);

    float T[2 * R_ + 2];  // pooled-bin dot products, bins fi-4 .. fi+5
#pragma unroll
    for (int j = 0; j < 2 * R_ + 2; ++j) {
      T[j] = f1v[0] * av[j].x + f1v[1] * av[j].y + f1v[2] * av[j].z +
             f1v[3] * av[j].w + f1v[4] * bv[j].x + f1v[5] * bv[j].y +
             f1v[6] * bv[j].z + f1v[7] * bv[j].w;
    }

    const int chBase = (2 * i) * (G_ * K_) + gk;
    float* o0 = outb + (size_t)chBase * HW_;
#pragma unroll
    for (int k = 0; k < K_; ++k) {
      const float val = w0 * T[k] + w1 * T[k + 1];
      // write-once streaming output: nt stores, no L2 dirty-line churn
      __builtin_nontemporal_store(val, o0 + (size_t)k * HW_);             // feat
      __builtin_nontemporal_store(val, o0 + (size_t)(G_ * K_ + k) * HW_); // geo
    }
  }
}

extern "C" void kernel_launch(void* const* d_in, const int* in_sizes, int n_in,
                              void* d_out, int out_size, void* d_ws, size_t ws_size,
                              hipStream_t stream) {
  const float* fmap1 = (const float*)d_in[0];
  const float* fmap2 = (const float*)d_in[1];
  const float* coords = (const float*)d_in[2];
  float* out = (float*)d_out;
  gacv_kernel<<<dim3(B_ * G_ * H_), dim3(TPB), 0, stream>>>(fmap1, fmap2, coords, out);
}

// Round 4
// 84.916 us; speedup vs baseline: 1.0331x; 1.0331x over previous
//
#include <hip/hip_runtime.h>

// GeometryAwareCostVolume — MI355X (gfx950)
//
// Algebraic restructuring vs reference:
//  * geo pyramid == feat pyramid: compute once, write twice.
//  * integer dx taps -> shared lerp fraction per level; 10 consecutive pooled
//    bins per level suffice.
//  * cost volume is linear in fmap2 -> pool fmap2 rows hierarchically first,
//    one dot8 per pooled bin; 131 MB cost volume never materialized.
//  * Split-half LDS layout + zero-padded pyramids: conflict-spread random
//    gathers, no per-tap clamp/select, base+imm ds_read_b128 addressing.
//
// Round 4: resubmission of round-3 source (bench infra failed; kernel never
// ran). Measured evidence so far:
//  * R1 (big LDS/VALU restructure): exactly neutral (85.2 -> 85.0 us).
//  * R2 (nt stores, L2/L3 bypass): +2.8 us regression.
// Model: the harness re-poisons a 256 MiB workspace per iteration (43.7 us
// fill + ~41 us dirty-line drain to HBM). The measured window ~= fill + drain
// ~= 85 us; the kernel's own ~15-20 us hides under the drain. Only changes
// that add direct HBM bus traffic during the drain (nt) move the number.
// Normal (cache-mediated) stores are optimal here. This is the harness-
// imposed memory floor: 2 x 256 MiB / 6.25 TB/s ~= 85 us.

namespace {
constexpr int B_ = 2, C_ = 64, H_ = 80, W_ = 160;
constexpr int G_ = 8, GC_ = 8, L_ = 4, K_ = 9, R_ = 4;
constexpr int HW_ = H_ * W_;
constexpr int NCH_ = 2 * L_ * G_ * K_;  // 576 output channels
constexpr int TPB = 192;                 // 3 waves; 160 active in compute phase
constexpr int P_ = 5;                    // zero-pad granules each side
constexpr float INV_SQRT_GC = 0.35355339059327373f;  // 1/sqrt(8)

// padded widths (granules of 4 floats) per level
constexpr int N0 = W_ + 2 * P_;       // 170
constexpr int N1 = W_ / 2 + 2 * P_;   // 90
constexpr int N2 = W_ / 4 + 2 * P_;   // 50
constexpr int N3 = W_ / 8 + 2 * P_;   // 30
// float offsets of the 8 arrays inside one shared buffer (A=c0..3, B=c4..7)
constexpr int OFF_A0 = 0;
constexpr int OFF_B0 = OFF_A0 + N0 * 4;
constexpr int OFF_A1 = OFF_B0 + N0 * 4;
constexpr int OFF_B1 = OFF_A1 + N1 * 4;
constexpr int OFF_A2 = OFF_B1 + N1 * 4;
constexpr int OFF_B2 = OFF_A2 + N2 * 4;
constexpr int OFF_A3 = OFF_B2 + N2 * 4;
constexpr int OFF_B3 = OFF_A3 + N3 * 4;
constexpr int STOT = OFF_B3 + N3 * 4;   // 2720 floats = 10.88 KB
__device__ constexpr int AOFF[8] = {OFF_A0, OFF_B0, OFF_A1, OFF_B1,
                                    OFF_A2, OFF_B2, OFF_A3, OFF_B3};
}

// pair-mean pool one level (both halves); WD = dst interior width
template <int SA, int SB, int DA, int DB, int WD>
__device__ __forceinline__ void pool_pair(float* S, int tid) {
  for (int idx = tid; idx < 2 * WD; idx += TPB) {
    const int srcOff = (idx & 1) ? SB : SA;
    const int dstOff = (idx & 1) ? DB : DA;
    const int t = idx >> 1;
    const float4 x = *(const float4*)(S + srcOff + (P_ + 2 * t) * 4);
    const float4 y = *(const float4*)(S + srcOff + (P_ + 2 * t) * 4 + 4);
    float4 r;
    r.x = 0.5f * (x.x + y.x);
    r.y = 0.5f * (x.y + y.y);
    r.z = 0.5f * (x.z + y.z);
    r.w = 0.5f * (x.w + y.w);
    *(float4*)(S + dstOff + (P_ + t) * 4) = r;
  }
}

__global__ __launch_bounds__(TPB) void gacv_kernel(
    const float* __restrict__ fmap1, const float* __restrict__ fmap2,
    const float* __restrict__ coords, float* __restrict__ out) {
  __shared__ __align__(16) float S[STOT];

  const int tid = threadIdx.x;
  const int bid = blockIdx.x;  // (b*G_ + g)*H_ + h
  const int h = bid % H_;
  const int bg = bid / H_;
  const int g = bg % G_;
  const int b = bg / G_;

  // ---- phase 1: zero guard bins (80 granules) + stage f2 row interior
  if (tid < 80) {
    const int arr = tid / 10;          // which of the 8 arrays
    const int j = tid % 10;            // which pad granule
    const int Wl = W_ >> (arr >> 1);
    const int gr = (j < P_) ? j : (Wl + j);  // [0,5) and [Wl+5, Wl+10)
    float4 z;
    z.x = z.y = z.z = z.w = 0.0f;
    *(float4*)(S + AOFF[arr] + gr * 4) = z;
  }
  const float* f2base = fmap2 + (size_t)(b * C_ + g * GC_) * HW_ + h * W_;
  for (int idx = tid; idx < W_ * GC_; idx += TPB) {
    const int v = idx % W_;            // lanes walk v => coalesced global reads
    const int c = idx / W_;
    // c 0..3 -> A0 half, c 4..7 -> B0 half (B0 contiguous after A0)
    S[OFF_A0 + (c >> 2) * (N0 * 4) + (v + P_) * 4 + (c & 3)] = f2base[c * HW_ + v];
  }
  __syncthreads();
  // ---- hierarchical pair-mean pyramid (matches reference association)
  pool_pair<OFF_A0, OFF_B0, OFF_A1, OFF_B1, 80>(S, tid);
  __syncthreads();
  pool_pair<OFF_A1, OFF_B1, OFF_A2, OFF_B2, 40>(S, tid);
  __syncthreads();
  pool_pair<OFF_A2, OFF_B2, OFF_A3, OFF_B3, 20>(S, tid);
  __syncthreads();

  if (tid >= W_) return;
  const int w = tid;

  // per-thread f1 fragment, pre-scaled by 1/sqrt(gc)
  const float* f1base = fmap1 + (size_t)(b * C_ + g * GC_) * HW_ + h * W_ + w;
  float f1v[GC_];
#pragma unroll
  for (int c = 0; c < GC_; ++c) f1v[c] = f1base[c * HW_] * INV_SQRT_GC;

  const float cx = coords[(b * H_ + h) * W_ + w];
  float* outb = out + (size_t)b * NCH_ * HW_ + h * W_ + w;
  const int gk = g * K_;

#pragma unroll
  for (int i = 0; i < L_; ++i) {
    const int Wl = W_ >> i;
    const float xl = cx * (1.0f / (1 << i));
    const float F = floorf(xl);
    int fi = (int)F;
    const float w1 = xl - F;  // shared lerp fraction (dx taps are integers)
    const float w0 = 1.0f - w1;
    fi = min(max(fi, 0), Wl - 1);  // safety clamp; no-op for valid coords

    // all 20 reads are base+imm off these two addresses; guard bins give the
    // exact zero the reference mask requires for out-of-range taps
    const float* Abase = S + AOFF[2 * i] + (fi + P_ - R_) * 4;
    const float* Bbase = S + AOFF[2 * i + 1] + (fi + P_ - R_) * 4;

    float4 av[2 * R_ + 2], bv[2 * R_ + 2];
#pragma unroll
    for (int j = 0; j < 2 * R_ + 2; ++j) av[j] = *(const float4*)(Abase + j * 4);
#pragma unroll
    for (int j = 0; j < 2 * R_ + 2; ++j) bv[j] = *(const float4*)(Bbase + j * 4);

    float T[2 * R_ + 2];  // pooled-bin dot products, bins fi-4 .. fi+5
#pragma unroll
    for (int j = 0; j < 2 * R_ + 2; ++j) {
      T[j] = f1v[0] * av[j].x + f1v[1] * av[j].y + f1v[2] * av[j].z +
             f1v[3] * av[j].w + f1v[4] * bv[j].x + f1v[5] * bv[j].y +
             f1v[6] * bv[j].z + f1v[7] * bv[j].w;
    }

    const int chBase = (2 * i) * (G_ * K_) + gk;
    float* o0 = outb + (size_t)chBase * HW_;
#pragma unroll
    for (int k = 0; k < K_; ++k) {
      const float val = w0 * T[k] + w1 * T[k + 1];
      o0[(size_t)k * HW_] = val;                     // "feat" copy
      o0[(size_t)(G_ * K_ + k) * HW_] = val;         // "geo" copy (identical)
    }
  }
}

extern "C" void kernel_launch(void* const* d_in, const int* in_sizes, int n_in,
                              void* d_out, int out_size, void* d_ws, size_t ws_size,
                              hipStream_t stream) {
  const float* fmap1 = (const float*)d_in[0];
  const float* fmap2 = (const float*)d_in[1];
  const float* coords = (const float*)d_in[2];
  float* out = (float*)d_out;
  gacv_kernel<<<dim3(B_ * G_ * H_), dim3(TPB), 0, stream>>>(fmap1, fmap2, coords, out);
}